// Round 1
// baseline (1175.319 us; speedup 1.0000x reference)
//
#include <hip/hip_runtime.h>
#include <math.h>

#define B_  8
#define H_  64
#define W_  64
#define C_  128
#define F_  256
#define K_  9
#define NOC 27

// ws layout (floats):
//   [0 .. 31104)        w_r : repacked offset weights [27][9][128]
//   [32768 .. 917504)   wi  : offset-conv output [B][H][W][27]
#define WS_WI_OFF 32768

// ---------------------------------------------------------------- kernel 0
__global__ __launch_bounds__(256) void repack_offw(const float* __restrict__ kofs,
                                                   float* __restrict__ w_r) {
    int idx = blockIdx.x * 256 + threadIdx.x;
    if (idx >= NOC * K_ * C_) return;
    int oc  = idx / (K_ * C_);
    int r   = idx % (K_ * C_);
    int tap = r / C_;
    int c   = r % C_;
    // kofs layout [ky][kx][c][oc] = [tap][c][oc]
    w_r[idx] = kofs[(tap * C_ + c) * NOC + oc];
}

// ---------------------------------------------------------------- kernel 1
// offset conv: wi[b,h,w,oc] = bias[oc] + sum_{tap,c} in[b,h+ky-1,w+kx-1,c] * K[tap,c,oc]
// block = (b, h, w-half of 32 px), 256 threads
__global__ __launch_bounds__(256) void offset_conv(const float* __restrict__ in,
                                                   const float* __restrict__ w_r,
                                                   const float* __restrict__ bias,
                                                   float* __restrict__ wi) {
    __shared__ __align__(16) float lds[3][34][132];   // [ky][x(-1..32)][c padded]
    int bid = blockIdx.x;
    int b   = bid >> 7;          // / 128
    int rem = bid & 127;
    int h   = rem >> 1;
    int w0  = (rem & 1) * 32;
    int t   = threadIdx.x;

    // stage 3 rows x 34 cols x 128 c (zero outside image)
    for (int idx = t; idx < 3 * 34 * 32; idx += 256) {
        int ky = idx / (34 * 32);
        int r  = idx % (34 * 32);
        int j  = r >> 5;                 // 0..33
        int c4 = r & 31;
        int y  = h - 1 + ky;
        int x  = w0 - 1 + j;
        float4 v = make_float4(0.f, 0.f, 0.f, 0.f);
        if ((unsigned)y < 64u && (unsigned)x < 64u) {
            v = *reinterpret_cast<const float4*>(
                    &in[(((b << 6) + y) * 64 + x) * 128 + (c4 << 2)]);
        }
        *reinterpret_cast<float4*>(&lds[ky][j][c4 << 2]) = v;
    }
    __syncthreads();

    if (t >= 224) return;                 // 7 groups x 32 px
    int px  = t & 31;
    int g   = t >> 5;                     // 0..6
    int oc0 = g * 4;                      // g=6 -> ocs 24,25,26 (+1 dummy)

    float acc0 = 0.f, acc1 = 0.f, acc2 = 0.f, acc3 = 0.f;
    for (int tap = 0; tap < 9; ++tap) {
        int ky = tap / 3, kx = tap % 3;
        const float* wr = &w_r[(oc0 * 9 + tap) * 128];
        const float* lp = &lds[ky][px + kx][0];
        #pragma unroll 8
        for (int c4 = 0; c4 < 32; ++c4) {
            float4 a  = *reinterpret_cast<const float4*>(&lp[c4 << 2]);
            float4 b0 = *reinterpret_cast<const float4*>(&wr[(c4 << 2)]);
            float4 b1 = *reinterpret_cast<const float4*>(&wr[1152 + (c4 << 2)]);
            float4 b2 = *reinterpret_cast<const float4*>(&wr[2304 + (c4 << 2)]);
            float4 b3 = *reinterpret_cast<const float4*>(&wr[3456 + (c4 << 2)]);
            acc0 = fmaf(a.x, b0.x, fmaf(a.y, b0.y, fmaf(a.z, b0.z, fmaf(a.w, b0.w, acc0))));
            acc1 = fmaf(a.x, b1.x, fmaf(a.y, b1.y, fmaf(a.z, b1.z, fmaf(a.w, b1.w, acc1))));
            acc2 = fmaf(a.x, b2.x, fmaf(a.y, b2.y, fmaf(a.z, b2.z, fmaf(a.w, b2.w, acc2))));
            acc3 = fmaf(a.x, b3.x, fmaf(a.y, b3.y, fmaf(a.z, b3.z, fmaf(a.w, b3.w, acc3))));
        }
    }
    int pixbase = (((b << 6) + h) * 64 + (w0 + px)) * NOC;
    wi[pixbase + oc0 + 0] = acc0 + bias[oc0 + 0];
    wi[pixbase + oc0 + 1] = acc1 + bias[oc0 + 1];
    wi[pixbase + oc0 + 2] = acc2 + bias[oc0 + 2];
    if (oc0 + 3 < NOC) wi[pixbase + oc0 + 3] = acc3 + bias[oc0 + 3];
}

// ---------------------------------------------------------------- kernel 2
// fused bilinear-sample + GEMM. block = (b, h, w-half of 32 px) x all 256 F
__global__ __launch_bounds__(256) void deform_main(const float* __restrict__ in,
                                                   const float* __restrict__ filt,
                                                   const float* __restrict__ wi,
                                                   float* __restrict__ out) {
    __shared__ __align__(16) float S[32][132];      // sampled cols for current tap
    __shared__ int   ipar[32][9][4];                // y0c,y1c,x0c,x1c
    __shared__ float fpar[32][9][4];                // w00,w01,w10,w11 (mask+valid folded)

    int bid = blockIdx.x;
    int b   = bid >> 7;
    int rem = bid & 127;
    int h   = rem >> 1;
    int w0  = (rem & 1) * 32;
    int t   = threadIdx.x;

    // per-(px,tap) sampling params
    for (int idx = t; idx < 32 * 9; idx += 256) {
        int px  = idx / 9, tap = idx % 9;
        int wp_ = w0 + px;
        const float* wp = &wi[WS_WI_OFF - WS_WI_OFF + (((b << 6) + h) * 64 + wp_) * NOC]; // wi already offset by caller
        float o1 = wp[tap], o2 = wp[9 + tap], mm = wp[18 + tap];
        float mask = 1.0f / (1.0f + expf(-mm));
        float py  = (float)(h   - 1 + tap / 3) + o1;
        float pxx = (float)(wp_ - 1 + tap % 3) + o2;
        float y0f = floorf(py), x0f = floorf(pxx);
        float wy1 = py - y0f,  wy0 = 1.f - wy1;
        float wx1 = pxx - x0f, wx0 = 1.f - wx1;
        float y1f = y0f + 1.f, x1f = x0f + 1.f;
        float vy0 = (y0f >= 0.f && y0f <= 63.f) ? 1.f : 0.f;
        float vy1 = (y1f >= 0.f && y1f <= 63.f) ? 1.f : 0.f;
        float vx0 = (x0f >= 0.f && x0f <= 63.f) ? 1.f : 0.f;
        float vx1 = (x1f >= 0.f && x1f <= 63.f) ? 1.f : 0.f;
        ipar[px][tap][0] = (int)fminf(fmaxf(y0f, 0.f), 63.f);
        ipar[px][tap][1] = (int)fminf(fmaxf(y1f, 0.f), 63.f);
        ipar[px][tap][2] = (int)fminf(fmaxf(x0f, 0.f), 63.f);
        ipar[px][tap][3] = (int)fminf(fmaxf(x1f, 0.f), 63.f);
        fpar[px][tap][0] = wy0 * wx0 * mask * vy0 * vx0;
        fpar[px][tap][1] = wy0 * wx1 * mask * vy0 * vx1;
        fpar[px][tap][2] = wy1 * wx0 * mask * vy1 * vx0;
        fpar[px][tap][3] = wy1 * wx1 * mask * vy1 * vx1;
    }

    float acc0[16], acc1[16];
    #pragma unroll
    for (int q = 0; q < 16; ++q) { acc0[q] = 0.f; acc1[q] = 0.f; }

    int j  = t & 15;          // f-group: f0 = 16*j
    int i  = t >> 4;          // px-pair: px = 2i, 2i+1
    int f0 = j << 4;
    int i2 = i << 1;

    const float4* inp = reinterpret_cast<const float4*>(in);

    for (int tap = 0; tap < 9; ++tap) {
        __syncthreads();      // params ready (tap 0) / previous GEMM done reading S
        // ---- stage S[32][128] for this tap (modulated bilinear gather)
        {
            int c4    = t & 31;
            int pbase = t >> 5;          // 0..7
            #pragma unroll
            for (int pp = 0; pp < 4; ++pp) {
                int px = pbase + (pp << 3);
                int y0 = ipar[px][tap][0], y1 = ipar[px][tap][1];
                int x0 = ipar[px][tap][2], x1 = ipar[px][tap][3];
                float w00 = fpar[px][tap][0], w01 = fpar[px][tap][1];
                float w10 = fpar[px][tap][2], w11 = fpar[px][tap][3];
                int rb = (b << 6);
                float4 v00 = inp[((rb + y0) * 64 + x0) * 32 + c4];
                float4 v01 = inp[((rb + y0) * 64 + x1) * 32 + c4];
                float4 v10 = inp[((rb + y1) * 64 + x0) * 32 + c4];
                float4 v11 = inp[((rb + y1) * 64 + x1) * 32 + c4];
                float4 s;
                s.x = w00 * v00.x + w01 * v01.x + w10 * v10.x + w11 * v11.x;
                s.y = w00 * v00.y + w01 * v01.y + w10 * v10.y + w11 * v11.y;
                s.z = w00 * v00.z + w01 * v01.z + w10 * v10.z + w11 * v11.z;
                s.w = w00 * v00.w + w01 * v01.w + w10 * v10.w + w11 * v11.w;
                *reinterpret_cast<float4*>(&S[px][c4 << 2]) = s;
            }
        }
        __syncthreads();
        // ---- GEMM chunk: out[px, f] += S[px, c] * filt[tap, c, f]
        const float* fb = &filt[tap * 128 * 256];
        #pragma unroll 1
        for (int c4 = 0; c4 < 32; ++c4) {
            float4 a0 = *reinterpret_cast<const float4*>(&S[i2][c4 << 2]);
            float4 a1 = *reinterpret_cast<const float4*>(&S[i2 + 1][c4 << 2]);
            const float* ap0 = reinterpret_cast<const float*>(&a0);
            const float* ap1 = reinterpret_cast<const float*>(&a1);
            #pragma unroll
            for (int cc = 0; cc < 4; ++cc) {
                float av0 = ap0[cc];
                float av1 = ap1[cc];
                const float* fr = fb + ((c4 << 2) + cc) * 256 + f0;
                float4 b0 = *reinterpret_cast<const float4*>(fr);
                float4 b1 = *reinterpret_cast<const float4*>(fr + 4);
                float4 b2 = *reinterpret_cast<const float4*>(fr + 8);
                float4 b3 = *reinterpret_cast<const float4*>(fr + 12);
                acc0[0]  = fmaf(av0, b0.x, acc0[0]);   acc1[0]  = fmaf(av1, b0.x, acc1[0]);
                acc0[1]  = fmaf(av0, b0.y, acc0[1]);   acc1[1]  = fmaf(av1, b0.y, acc1[1]);
                acc0[2]  = fmaf(av0, b0.z, acc0[2]);   acc1[2]  = fmaf(av1, b0.z, acc1[2]);
                acc0[3]  = fmaf(av0, b0.w, acc0[3]);   acc1[3]  = fmaf(av1, b0.w, acc1[3]);
                acc0[4]  = fmaf(av0, b1.x, acc0[4]);   acc1[4]  = fmaf(av1, b1.x, acc1[4]);
                acc0[5]  = fmaf(av0, b1.y, acc0[5]);   acc1[5]  = fmaf(av1, b1.y, acc1[5]);
                acc0[6]  = fmaf(av0, b1.z, acc0[6]);   acc1[6]  = fmaf(av1, b1.z, acc1[6]);
                acc0[7]  = fmaf(av0, b1.w, acc0[7]);   acc1[7]  = fmaf(av1, b1.w, acc1[7]);
                acc0[8]  = fmaf(av0, b2.x, acc0[8]);   acc1[8]  = fmaf(av1, b2.x, acc1[8]);
                acc0[9]  = fmaf(av0, b2.y, acc0[9]);   acc1[9]  = fmaf(av1, b2.y, acc1[9]);
                acc0[10] = fmaf(av0, b2.z, acc0[10]);  acc1[10] = fmaf(av1, b2.z, acc1[10]);
                acc0[11] = fmaf(av0, b2.w, acc0[11]);  acc1[11] = fmaf(av1, b2.w, acc1[11]);
                acc0[12] = fmaf(av0, b3.x, acc0[12]);  acc1[12] = fmaf(av1, b3.x, acc1[12]);
                acc0[13] = fmaf(av0, b3.y, acc0[13]);  acc1[13] = fmaf(av1, b3.y, acc1[13]);
                acc0[14] = fmaf(av0, b3.z, acc0[14]);  acc1[14] = fmaf(av1, b3.z, acc1[14]);
                acc0[15] = fmaf(av0, b3.w, acc0[15]);  acc1[15] = fmaf(av1, b3.w, acc1[15]);
            }
        }
    }

    // epilogue
    int wpix = w0 + i2;
    float* orow0 = &out[(((b << 6) + h) * 64 + wpix) * 256 + f0];
    float* orow1 = orow0 + 256;
    *reinterpret_cast<float4*>(orow0 + 0)  = make_float4(acc0[0],  acc0[1],  acc0[2],  acc0[3]);
    *reinterpret_cast<float4*>(orow0 + 4)  = make_float4(acc0[4],  acc0[5],  acc0[6],  acc0[7]);
    *reinterpret_cast<float4*>(orow0 + 8)  = make_float4(acc0[8],  acc0[9],  acc0[10], acc0[11]);
    *reinterpret_cast<float4*>(orow0 + 12) = make_float4(acc0[12], acc0[13], acc0[14], acc0[15]);
    *reinterpret_cast<float4*>(orow1 + 0)  = make_float4(acc1[0],  acc1[1],  acc1[2],  acc1[3]);
    *reinterpret_cast<float4*>(orow1 + 4)  = make_float4(acc1[4],  acc1[5],  acc1[6],  acc1[7]);
    *reinterpret_cast<float4*>(orow1 + 8)  = make_float4(acc1[8],  acc1[9],  acc1[10], acc1[11]);
    *reinterpret_cast<float4*>(orow1 + 12) = make_float4(acc1[12], acc1[13], acc1[14], acc1[15]);
}

// ---------------------------------------------------------------- launch
extern "C" void kernel_launch(void* const* d_in, const int* in_sizes, int n_in,
                              void* d_out, int out_size, void* d_ws, size_t ws_size,
                              hipStream_t stream) {
    const float* in    = (const float*)d_in[0];
    const float* kofs  = (const float*)d_in[1];
    const float* bias  = (const float*)d_in[2];
    const float* filt  = (const float*)d_in[3];
    float* out = (float*)d_out;
    float* ws  = (float*)d_ws;

    float* w_r = ws;                 // 31104 floats
    float* wi  = ws + WS_WI_OFF;     // 884736 floats

    hipLaunchKernelGGL(repack_offw, dim3((NOC * K_ * C_ + 255) / 256), dim3(256), 0, stream,
                       kofs, w_r);
    hipLaunchKernelGGL(offset_conv, dim3(B_ * H_ * 2), dim3(256), 0, stream,
                       in, w_r, bias, wi);
    hipLaunchKernelGGL(deform_main, dim3(B_ * H_ * 2), dim3(256), 0, stream,
                       in, filt, wi, out);
}

// Round 2
// 156.153 us; speedup vs baseline: 7.5267x; 7.5267x over previous
//
#include <hip/hip_runtime.h>
#include <hip/hip_bf16.h>
#include <math.h>

#define B_  8
#define H_  64
#define W_  64
#define C_  128
#define F_  256
#define NOC 27

typedef float f32x4  __attribute__((ext_vector_type(4)));
typedef short bf16x8 __attribute__((ext_vector_type(8)));

// ws layout (float units):
//   woffT : bf16[9][32][128]   @ 0        (73728 B)
//   filtT : bf16[9][256][128]  @ 32768    (589824 B)
//   wi32  : float[32768][32]   @ 180224   (4 MB)
#define FILTT_OFF_F 32768
#define WI32_OFF_F  180224

static __device__ __forceinline__ unsigned pk2(float a, float b) {
    __hip_bfloat162 h = __float22bfloat162_rn(make_float2(a, b));
    union { __hip_bfloat162 h2; unsigned u; } cv;
    cv.h2 = h;
    return cv.u;
}

// ---------------------------------------------------------------- repack
// woffT[tap][oc(32,pad0)][c] = kofs[tap][c][oc] ; filtT[tap][f][c] = filt[tap][c][f]
__global__ __launch_bounds__(256) void repack(const float* __restrict__ kofs,
                                              const float* __restrict__ filt,
                                              unsigned short* __restrict__ woffT,
                                              unsigned short* __restrict__ filtT) {
    int idx = blockIdx.x * 256 + threadIdx.x;
    if (idx < 9 * 32 * 128) {
        int tap = idx >> 12;
        int r   = idx & 4095;
        int oc  = r >> 7;
        int c   = r & 127;
        float v = (oc < NOC) ? kofs[(tap * C_ + c) * NOC + oc] : 0.f;
        union { __hip_bfloat16 h; unsigned short u; } cv;
        cv.h = __float2bfloat16(v);
        woffT[idx] = cv.u;
        return;
    }
    int idx2 = idx - 9 * 32 * 128;
    if (idx2 < 9 * 256 * 128) {
        int tap = idx2 / 32768;
        int r   = idx2 & 32767;
        int f   = r >> 7;
        int c   = r & 127;
        float v = filt[(tap * C_ + c) * F_ + f];
        union { __hip_bfloat16 h; unsigned short u; } cv;
        cv.h = __float2bfloat16(v);
        filtT[idx2] = cv.u;
    }
}

// ---------------------------------------------------------------- offset conv (MFMA)
// wi32[pix][oc] = bias[oc] + sum_{tap,c} in[b, h+ky-1, w+kx-1, c] * woffT[tap][oc][c]
// block = 64 px (one image row), 1 wave; wave tile 64px x 32oc
__global__ __launch_bounds__(64) void offset_conv_mfma(const float* __restrict__ in,
                                                       const unsigned short* __restrict__ woffT,
                                                       const float* __restrict__ bias,
                                                       float* __restrict__ wi32) {
    __shared__ __align__(16) unsigned char Ab[64 * 256];   // A tile bf16, XOR-swizzled

    int t    = threadIdx.x;
    int bb   = blockIdx.x >> 6;
    int hh   = blockIdx.x & 63;
    int pix0 = blockIdx.x << 6;

    int row = t & 15;
    int kg  = t >> 4;
    int c4  = t & 31;
    int pxh = t >> 5;      // 0..1

    f32x4 z = {0.f, 0.f, 0.f, 0.f};
    f32x4 acc[4][2];
    #pragma unroll
    for (int m = 0; m < 4; ++m) { acc[m][0] = z; acc[m][1] = z; }

    for (int tap = 0; tap < 9; ++tap) {
        int ky = tap / 3, kx = tap - ky * 3;
        int y  = hh + ky - 1;
        bool yok = (unsigned)y < 64u;
        __syncthreads();
        #pragma unroll 4
        for (int pp = 0; pp < 32; ++pp) {
            int px = pxh * 32 + pp;
            int x  = px + kx - 1;
            float4 v = make_float4(0.f, 0.f, 0.f, 0.f);
            if (yok && (unsigned)x < 64u)
                v = *(const float4*)((const char*)in +
                        (size_t)(((bb << 6) + y) * 64 + x) * 512 + (c4 << 4));
            *(uint2*)(Ab + ((px << 8) + ((c4 << 3) ^ ((px & 7) << 4)))) =
                make_uint2(pk2(v.x, v.y), pk2(v.z, v.w));
        }
        __syncthreads();
        const unsigned short* bp = woffT + (size_t)tap * 4096 + (size_t)row * 128 + kg * 8;
        #pragma unroll
        for (int ks = 0; ks < 4; ++ks) {
            bf16x8 a[4], b[2];
            #pragma unroll
            for (int m = 0; m < 4; ++m)
                a[m] = *(const bf16x8*)(Ab + (((m * 16 + row) << 8) +
                            ((ks * 64 + kg * 16) ^ ((row & 7) << 4))));
            #pragma unroll
            for (int n = 0; n < 2; ++n)
                b[n] = *(const bf16x8*)(bp + n * 2048 + ks * 32);
            #pragma unroll
            for (int m = 0; m < 4; ++m)
                #pragma unroll
                for (int n = 0; n < 2; ++n)
                    acc[m][n] = __builtin_amdgcn_mfma_f32_16x16x32_bf16(a[m], b[n], acc[m][n], 0, 0, 0);
        }
    }

    #pragma unroll
    for (int n = 0; n < 2; ++n) {
        int oc = n * 16 + row;
        float bv = (oc < NOC) ? bias[oc] : 0.f;
        #pragma unroll
        for (int m = 0; m < 4; ++m)
            #pragma unroll
            for (int r = 0; r < 4; ++r) {
                int px = m * 16 + kg * 4 + r;
                wi32[(size_t)(pix0 + px) * 32 + oc] = acc[m][n][r] + bv;
            }
    }
}

// ---------------------------------------------------------------- main deform conv (MFMA)
// block = one image row (64 px) x 256 F, 4 waves (wave w: F in [64w, 64w+64))
__global__ __launch_bounds__(256) void deform_mfma(const float* __restrict__ in,
                                                   const unsigned short* __restrict__ filtT,
                                                   const float* __restrict__ wi32,
                                                   float* __restrict__ out) {
    __shared__ __align__(16) unsigned char Ab[64 * 256];   // A tile bf16, XOR-swizzled
    __shared__ __align__(16) int   coff[64][9][4];         // corner byte offsets (clamped)
    __shared__ __align__(16) float fwgt[64][9][4];         // bilinear*mask*valid weights

    int t    = threadIdx.x;
    int bb   = blockIdx.x >> 6;
    int hh   = blockIdx.x & 63;
    int pix0 = blockIdx.x << 6;

    // ---- per-(px,tap) sampling params
    for (int it = t; it < 576; it += 256) {
        int tap = it >> 6;
        int px  = it & 63;
        const float* wp = wi32 + (size_t)(pix0 + px) * 32;
        float o1 = wp[tap], o2 = wp[9 + tap], mm = wp[18 + tap];
        float mask = 1.f / (1.f + __expf(-mm));
        int ky = tap / 3, kx = tap - ky * 3;
        float py  = (float)(hh - 1 + ky) + o1;
        float pxx = (float)(px - 1 + kx) + o2;
        float y0f = floorf(py), x0f = floorf(pxx);
        float wy1 = py - y0f,  wy0 = 1.f - wy1;
        float wx1 = pxx - x0f, wx0 = 1.f - wx1;
        float vy0 = (y0f >=  0.f && y0f <= 63.f) ? 1.f : 0.f;
        float vy1 = (y0f >= -1.f && y0f <= 62.f) ? 1.f : 0.f;
        float vx0 = (x0f >=  0.f && x0f <= 63.f) ? 1.f : 0.f;
        float vx1 = (x0f >= -1.f && x0f <= 62.f) ? 1.f : 0.f;
        int y0 = (int)fminf(fmaxf(y0f,       0.f), 63.f);
        int y1 = (int)fminf(fmaxf(y0f + 1.f, 0.f), 63.f);
        int x0 = (int)fminf(fmaxf(x0f,       0.f), 63.f);
        int x1 = (int)fminf(fmaxf(x0f + 1.f, 0.f), 63.f);
        int base = bb << 12;
        coff[px][tap][0] = (base + (y0 << 6) + x0) << 9;
        coff[px][tap][1] = (base + (y0 << 6) + x1) << 9;
        coff[px][tap][2] = (base + (y1 << 6) + x0) << 9;
        coff[px][tap][3] = (base + (y1 << 6) + x1) << 9;
        fwgt[px][tap][0] = wy0 * wx0 * mask * vy0 * vx0;
        fwgt[px][tap][1] = wy0 * wx1 * mask * vy0 * vx1;
        fwgt[px][tap][2] = wy1 * wx0 * mask * vy1 * vx0;
        fwgt[px][tap][3] = wy1 * wx1 * mask * vy1 * vx1;
    }

    int lane = t & 63, wv = t >> 6;
    int row = lane & 15, kg = lane >> 4;
    int fb  = wv << 6;
    int c4  = t & 31;
    int pxg = t >> 5;      // 0..7

    f32x4 z = {0.f, 0.f, 0.f, 0.f};
    f32x4 acc[4][4];
    #pragma unroll
    for (int m = 0; m < 4; ++m)
        #pragma unroll
        for (int n = 0; n < 4; ++n) acc[m][n] = z;

    const char* ib = (const char*)in;

    for (int tap = 0; tap < 9; ++tap) {
        __syncthreads();    // params ready / prev MFMA done with Ab
        // ---- modulated bilinear gather -> bf16 -> swizzled LDS
        #pragma unroll
        for (int pp = 0; pp < 8; ++pp) {
            int px = pxg + (pp << 3);
            int4   co = *(const int4*)&coff[px][tap][0];
            float4 wg = *(const float4*)&fwgt[px][tap][0];
            int cb = c4 << 4;
            float4 v00 = *(const float4*)(ib + co.x + cb);
            float4 v01 = *(const float4*)(ib + co.y + cb);
            float4 v10 = *(const float4*)(ib + co.z + cb);
            float4 v11 = *(const float4*)(ib + co.w + cb);
            float sx = wg.x * v00.x + wg.y * v01.x + wg.z * v10.x + wg.w * v11.x;
            float sy = wg.x * v00.y + wg.y * v01.y + wg.z * v10.y + wg.w * v11.y;
            float sz = wg.x * v00.z + wg.y * v01.z + wg.z * v10.z + wg.w * v11.z;
            float sw = wg.x * v00.w + wg.y * v01.w + wg.z * v10.w + wg.w * v11.w;
            *(uint2*)(Ab + ((px << 8) + ((c4 << 3) ^ ((px & 7) << 4)))) =
                make_uint2(pk2(sx, sy), pk2(sz, sw));
        }
        __syncthreads();
        // ---- MFMA: acc[m][n] += A[64x128] * B[128x64]
        const unsigned short* bp = filtT + (size_t)tap * 32768 + (size_t)(fb + row) * 128 + kg * 8;
        #pragma unroll
        for (int ks = 0; ks < 4; ++ks) {
            bf16x8 a[4], b[4];
            #pragma unroll
            for (int m = 0; m < 4; ++m)
                a[m] = *(const bf16x8*)(Ab + (((m * 16 + row) << 8) +
                            ((ks * 64 + kg * 16) ^ ((row & 7) << 4))));
            #pragma unroll
            for (int n = 0; n < 4; ++n)
                b[n] = *(const bf16x8*)(bp + n * 2048 + ks * 32);
            #pragma unroll
            for (int m = 0; m < 4; ++m)
                #pragma unroll
                for (int n = 0; n < 4; ++n)
                    acc[m][n] = __builtin_amdgcn_mfma_f32_16x16x32_bf16(a[m], b[n], acc[m][n], 0, 0, 0);
        }
    }

    // ---- epilogue: D row = 4*(lane>>4)+r, col = lane&15
    #pragma unroll
    for (int m = 0; m < 4; ++m)
        #pragma unroll
        for (int r = 0; r < 4; ++r) {
            int px = m * 16 + kg * 4 + r;
            float* op = out + (size_t)(pix0 + px) * 256 + fb + row;
            op[0]  = acc[m][0][r];
            op[16] = acc[m][1][r];
            op[32] = acc[m][2][r];
            op[48] = acc[m][3][r];
        }
}

// ---------------------------------------------------------------- launch
extern "C" void kernel_launch(void* const* d_in, const int* in_sizes, int n_in,
                              void* d_out, int out_size, void* d_ws, size_t ws_size,
                              hipStream_t stream) {
    const float* in   = (const float*)d_in[0];
    const float* kofs = (const float*)d_in[1];
    const float* bias = (const float*)d_in[2];
    const float* filt = (const float*)d_in[3];
    float* out = (float*)d_out;
    float* ws  = (float*)d_ws;

    unsigned short* woffT = (unsigned short*)ws;
    unsigned short* filtT = (unsigned short*)(ws + FILTT_OFF_F);
    float*          wi32  = ws + WI32_OFF_F;

    hipLaunchKernelGGL(repack, dim3(1296), dim3(256), 0, stream, kofs, filt, woffT, filtT);
    hipLaunchKernelGGL(offset_conv_mfma, dim3(512), dim3(64), 0, stream, in, woffT, bias, wi32);
    hipLaunchKernelGGL(deform_mfma, dim3(512), dim3(256), 0, stream, in, filtT, wi32, out);
}

// Round 3
// 129.344 us; speedup vs baseline: 9.0868x; 1.2073x over previous
//
#include <hip/hip_runtime.h>
#include <hip/hip_bf16.h>
#include <math.h>

#define B_  8
#define H_  64
#define W_  64
#define C_  128
#define F_  256
#define NOC 27

typedef float f32x4  __attribute__((ext_vector_type(4)));
typedef short bf16x8 __attribute__((ext_vector_type(8)));

// ws layout (float units):
//   woffT : bf16[9][32][128]   @ 0        (73728 B)
//   filtT : bf16[9][256][128]  @ 32768    (589824 B)
//   wi32  : float[32768][32]   @ 180224   (4 MB)
#define FILTT_OFF_F 32768
#define WI32_OFF_F  180224

static __device__ __forceinline__ unsigned pk2(float a, float b) {
    __hip_bfloat162 h = __float22bfloat162_rn(make_float2(a, b));
    union { __hip_bfloat162 h2; unsigned u; } cv;
    cv.h2 = h;
    return cv.u;
}

// ---------------------------------------------------------------- repack
__global__ __launch_bounds__(256) void repack(const float* __restrict__ kofs,
                                              const float* __restrict__ filt,
                                              unsigned short* __restrict__ woffT,
                                              unsigned short* __restrict__ filtT) {
    int idx = blockIdx.x * 256 + threadIdx.x;
    if (idx < 9 * 32 * 128) {
        int tap = idx >> 12;
        int r   = idx & 4095;
        int oc  = r >> 7;
        int c   = r & 127;
        float v = (oc < NOC) ? kofs[(tap * C_ + c) * NOC + oc] : 0.f;
        union { __hip_bfloat16 h; unsigned short u; } cv;
        cv.h = __float2bfloat16(v);
        woffT[idx] = cv.u;
        return;
    }
    int idx2 = idx - 9 * 32 * 128;
    if (idx2 < 9 * 256 * 128) {
        int tap = idx2 / 32768;
        int r   = idx2 & 32767;
        int f   = r >> 7;
        int c   = r & 127;
        float v = filt[(tap * C_ + c) * F_ + f];
        union { __hip_bfloat16 h; unsigned short u; } cv;
        cv.h = __float2bfloat16(v);
        filtT[idx2] = cv.u;
    }
}

// ---------------------------------------------------------------- offset conv (MFMA)
// block = one image row (64 px), 256 threads / 4 waves; wave w: px [16w,16w+16) x 32 oc.
// Stages the 3x66x128 bf16 input window once (XOR-swizzled), single barrier.
__global__ __launch_bounds__(256) void offset_conv_mfma(const float* __restrict__ in,
                                                        const unsigned short* __restrict__ woffT,
                                                        const float* __restrict__ bias,
                                                        float* __restrict__ wi32) {
    __shared__ __align__(16) unsigned char win[3 * 66 * 256];   // 50688 B

    int t    = threadIdx.x;
    int bb   = blockIdx.x >> 6;
    int hh   = blockIdx.x & 63;
    int pix0 = blockIdx.x << 6;

    // ---- stage window: rows hh-1..hh+1, x = -1..64 (xi = x+1 in 0..65)
    for (int idx = t; idx < 3 * 66 * 32; idx += 256) {
        int ky = idx / (66 * 32);
        int r  = idx % (66 * 32);
        int xi = r >> 5;            // 0..65
        int c4 = r & 31;
        int y  = hh + ky - 1;
        int x  = xi - 1;
        float4 v = make_float4(0.f, 0.f, 0.f, 0.f);
        if ((unsigned)y < 64u && (unsigned)x < 64u)
            v = *(const float4*)((const char*)in +
                    ((size_t)(((bb << 6) + y) * 64 + x) << 9) + (c4 << 4));
        *(uint2*)(win + ky * 16896 + xi * 256 + ((c4 << 3) ^ ((xi & 7) << 4))) =
            make_uint2(pk2(v.x, v.y), pk2(v.z, v.w));
    }
    __syncthreads();

    int lane = t & 63, wv = t >> 6;
    int row  = lane & 15, kg = lane >> 4;
    int px0  = wv << 4;

    f32x4 z = {0.f, 0.f, 0.f, 0.f};
    f32x4 acc[2] = {z, z};

    for (int tap = 0; tap < 9; ++tap) {
        int ky = tap / 3, kx = tap - ky * 3;
        int xi = px0 + row + kx;                 // (px + kx - 1) + 1
        const unsigned char* arow = win + ky * 16896 + xi * 256;
        int sw = (xi & 7) << 4;
        const unsigned short* bp = woffT + (size_t)tap * 4096 + (size_t)row * 128 + kg * 8;
        #pragma unroll
        for (int ks = 0; ks < 4; ++ks) {
            bf16x8 a  = *(const bf16x8*)(arow + ((ks * 64 + kg * 16) ^ sw));
            bf16x8 b0 = *(const bf16x8*)(bp + ks * 32);
            bf16x8 b1 = *(const bf16x8*)(bp + 2048 + ks * 32);
            acc[0] = __builtin_amdgcn_mfma_f32_16x16x32_bf16(a, b0, acc[0], 0, 0, 0);
            acc[1] = __builtin_amdgcn_mfma_f32_16x16x32_bf16(a, b1, acc[1], 0, 0, 0);
        }
    }

    #pragma unroll
    for (int n = 0; n < 2; ++n) {
        int oc = n * 16 + row;
        float bv = (oc < NOC) ? bias[oc] : 0.f;
        #pragma unroll
        for (int r = 0; r < 4; ++r) {
            int px = px0 + kg * 4 + r;
            wi32[(size_t)(pix0 + px) * 32 + oc] = acc[n][r] + bv;
        }
    }
}

// ---------------------------------------------------------------- main deform conv (MFMA)
// block = 32 px x 256 F, 4 waves (wave w: F in [64w,64w+64), all 32 px).
// Double-buffered A-tile; per tap: MFMA(tap) then gather(tap+1), one barrier.
__global__ __launch_bounds__(256) void deform_mfma(const float* __restrict__ in,
                                                   const unsigned short* __restrict__ filtT,
                                                   const float* __restrict__ wi32,
                                                   float* __restrict__ out) {
    __shared__ __align__(16) unsigned char Ab[2][32 * 256];   // 16 KB, XOR-swizzled
    __shared__ __align__(16) int   coff[32][9][4];
    __shared__ __align__(16) float fwgt[32][9][4];

    int t    = threadIdx.x;
    int bid  = blockIdx.x;
    int bb   = bid >> 7;
    int rem  = bid & 127;
    int hh   = rem >> 1;
    int w0   = (rem & 1) << 5;
    int pix0 = bid << 5;

    // ---- per-(px,tap) sampling params (288 items)
    for (int it = t; it < 288; it += 256) {
        int tap = it >> 5;
        int px  = it & 31;
        const float* wp = wi32 + (size_t)(pix0 + px) * 32;
        float o1 = wp[tap], o2 = wp[9 + tap], mm = wp[18 + tap];
        float mask = 1.f / (1.f + __expf(-mm));
        int ky = tap / 3, kx = tap - ky * 3;
        float py  = (float)(hh - 1 + ky) + o1;
        float pxx = (float)(w0 + px - 1 + kx) + o2;
        float y0f = floorf(py), x0f = floorf(pxx);
        float wy1 = py - y0f,  wy0 = 1.f - wy1;
        float wx1 = pxx - x0f, wx0 = 1.f - wx1;
        float vy0 = (y0f >=  0.f && y0f <= 63.f) ? 1.f : 0.f;
        float vy1 = (y0f >= -1.f && y0f <= 62.f) ? 1.f : 0.f;
        float vx0 = (x0f >=  0.f && x0f <= 63.f) ? 1.f : 0.f;
        float vx1 = (x0f >= -1.f && x0f <= 62.f) ? 1.f : 0.f;
        int y0 = (int)fminf(fmaxf(y0f,       0.f), 63.f);
        int y1 = (int)fminf(fmaxf(y0f + 1.f, 0.f), 63.f);
        int x0 = (int)fminf(fmaxf(x0f,       0.f), 63.f);
        int x1 = (int)fminf(fmaxf(x0f + 1.f, 0.f), 63.f);
        int base = bb << 12;
        coff[px][tap][0] = (base + (y0 << 6) + x0) << 9;
        coff[px][tap][1] = (base + (y0 << 6) + x1) << 9;
        coff[px][tap][2] = (base + (y1 << 6) + x0) << 9;
        coff[px][tap][3] = (base + (y1 << 6) + x1) << 9;
        fwgt[px][tap][0] = wy0 * wx0 * mask * vy0 * vx0;
        fwgt[px][tap][1] = wy0 * wx1 * mask * vy0 * vx1;
        fwgt[px][tap][2] = wy1 * wx0 * mask * vy1 * vx0;
        fwgt[px][tap][3] = wy1 * wx1 * mask * vy1 * vx1;
    }

    int lane = t & 63, wv = t >> 6;
    int row  = lane & 15, kg = lane >> 4;
    int fb   = wv << 6;
    int c4   = t & 31;
    int pxg  = t >> 5;      // 0..7

    const char* ib = (const char*)in;

    auto gather = [&](int tp, int buf) {
        #pragma unroll
        for (int pp = 0; pp < 4; ++pp) {
            int px = pxg + (pp << 3);
            int4   co = *(const int4*)&coff[px][tp][0];
            float4 wg = *(const float4*)&fwgt[px][tp][0];
            int cb = c4 << 4;
            float4 v00 = *(const float4*)(ib + co.x + cb);
            float4 v01 = *(const float4*)(ib + co.y + cb);
            float4 v10 = *(const float4*)(ib + co.z + cb);
            float4 v11 = *(const float4*)(ib + co.w + cb);
            float sx = wg.x * v00.x + wg.y * v01.x + wg.z * v10.x + wg.w * v11.x;
            float sy = wg.x * v00.y + wg.y * v01.y + wg.z * v10.y + wg.w * v11.y;
            float sz = wg.x * v00.z + wg.y * v01.z + wg.z * v10.z + wg.w * v11.z;
            float sw = wg.x * v00.w + wg.y * v01.w + wg.z * v10.w + wg.w * v11.w;
            *(uint2*)(Ab[buf] + ((px << 8) + ((c4 << 3) ^ ((px & 7) << 4)))) =
                make_uint2(pk2(sx, sy), pk2(sz, sw));
        }
    };

    f32x4 z = {0.f, 0.f, 0.f, 0.f};
    f32x4 acc[2][4];
    #pragma unroll
    for (int m = 0; m < 2; ++m)
        #pragma unroll
        for (int n = 0; n < 4; ++n) acc[m][n] = z;

    __syncthreads();          // params ready
    gather(0, 0);
    __syncthreads();          // buf0 ready

    for (int tap = 0; tap < 9; ++tap) {
        int cur = tap & 1;
        // ---- MFMA on current buffer
        const unsigned short* bp = filtT + (size_t)tap * 32768 + (size_t)(fb + row) * 128 + kg * 8;
        #pragma unroll
        for (int ks = 0; ks < 4; ++ks) {
            bf16x8 a[2], bfr[4];
            #pragma unroll
            for (int m = 0; m < 2; ++m)
                a[m] = *(const bf16x8*)(Ab[cur] + (((m * 16 + row) << 8) +
                            ((ks * 64 + kg * 16) ^ ((row & 7) << 4))));
            #pragma unroll
            for (int n = 0; n < 4; ++n)
                bfr[n] = *(const bf16x8*)(bp + n * 2048 + ks * 32);
            #pragma unroll
            for (int m = 0; m < 2; ++m)
                #pragma unroll
                for (int n = 0; n < 4; ++n)
                    acc[m][n] = __builtin_amdgcn_mfma_f32_16x16x32_bf16(a[m], bfr[n], acc[m][n], 0, 0, 0);
        }
        // ---- prefetch-gather next tap into other buffer
        if (tap < 8) gather(tap + 1, cur ^ 1);
        __syncthreads();
    }

    // ---- epilogue
    #pragma unroll
    for (int m = 0; m < 2; ++m)
        #pragma unroll
        for (int r = 0; r < 4; ++r) {
            int px = m * 16 + kg * 4 + r;
            float* op = out + (size_t)(pix0 + px) * 256 + fb + row;
            op[0]  = acc[m][0][r];
            op[16] = acc[m][1][r];
            op[32] = acc[m][2][r];
            op[48] = acc[m][3][r];
        }
}

// ---------------------------------------------------------------- launch
extern "C" void kernel_launch(void* const* d_in, const int* in_sizes, int n_in,
                              void* d_out, int out_size, void* d_ws, size_t ws_size,
                              hipStream_t stream) {
    const float* in   = (const float*)d_in[0];
    const float* kofs = (const float*)d_in[1];
    const float* bias = (const float*)d_in[2];
    const float* filt = (const float*)d_in[3];
    float* out = (float*)d_out;
    float* ws  = (float*)d_ws;

    unsigned short* woffT = (unsigned short*)ws;
    unsigned short* filtT = (unsigned short*)(ws + FILTT_OFF_F);
    float*          wi32  = ws + WI32_OFF_F;

    hipLaunchKernelGGL(repack, dim3(1296), dim3(256), 0, stream, kofs, filt, woffT, filtT);
    hipLaunchKernelGGL(offset_conv_mfma, dim3(512), dim3(256), 0, stream, in, woffT, bias, wi32);
    hipLaunchKernelGGL(deform_mfma, dim3(1024), dim3(256), 0, stream, in, filtT, wi32, out);
}

// Round 4
// 121.267 us; speedup vs baseline: 9.6920x; 1.0666x over previous
//
#include <hip/hip_runtime.h>
#include <hip/hip_bf16.h>
#include <math.h>

#define B_  8
#define H_  64
#define W_  64
#define C_  128
#define F_  256
#define NOC 27

typedef float f32x4  __attribute__((ext_vector_type(4)));
typedef short bf16x8 __attribute__((ext_vector_type(8)));

// ws layout (float units):
//   woffT : bf16[9][32][128]   @ 0        (73728 B)
//   filtT : bf16[9][256][128]  @ 32768    (589824 B)
//   wi32  : float[32768][32]   @ 180224   (4 MB)
#define FILTT_OFF_F 32768
#define WI32_OFF_F  180224

static __device__ __forceinline__ unsigned pk2(float a, float b) {
    __hip_bfloat162 h = __float22bfloat162_rn(make_float2(a, b));
    union { __hip_bfloat162 h2; unsigned u; } cv;
    cv.h2 = h;
    return cv.u;
}

// ---------------------------------------------------------------- repack
__global__ __launch_bounds__(256) void repack(const float* __restrict__ kofs,
                                              const float* __restrict__ filt,
                                              unsigned short* __restrict__ woffT,
                                              unsigned short* __restrict__ filtT) {
    int idx = blockIdx.x * 256 + threadIdx.x;
    if (idx < 9 * 32 * 128) {
        int tap = idx >> 12;
        int r   = idx & 4095;
        int oc  = r >> 7;
        int c   = r & 127;
        float v = (oc < NOC) ? kofs[(tap * C_ + c) * NOC + oc] : 0.f;
        union { __hip_bfloat16 h; unsigned short u; } cv;
        cv.h = __float2bfloat16(v);
        woffT[idx] = cv.u;
        return;
    }
    int idx2 = idx - 9 * 32 * 128;
    if (idx2 < 9 * 256 * 128) {
        int tap = idx2 / 32768;
        int r   = idx2 & 32767;
        int f   = r >> 7;
        int c   = r & 127;
        float v = filt[(tap * C_ + c) * F_ + f];
        union { __hip_bfloat16 h; unsigned short u; } cv;
        cv.h = __float2bfloat16(v);
        filtT[idx2] = cv.u;
    }
}

// ---------------------------------------------------------------- offset conv (MFMA)
// block = one image row (64 px), 256 threads / 4 waves; wave w: px [16w,16w+16) x 32 oc.
// XCD-swizzled: each XCD gets one contiguous 64-row chunk (= one image).
__global__ __launch_bounds__(256) void offset_conv_mfma(const float* __restrict__ in,
                                                        const unsigned short* __restrict__ woffT,
                                                        const float* __restrict__ bias,
                                                        float* __restrict__ wi32) {
    __shared__ __align__(16) unsigned char win[3 * 66 * 256];   // 50688 B

    int t    = threadIdx.x;
    int bid  = blockIdx.x;
    int lg   = ((bid & 7) << 6) | (bid >> 3);       // bijective XCD swizzle (512 = 8*64)
    int bb   = lg >> 6;
    int hh   = lg & 63;
    int pix0 = lg << 6;

    // ---- stage window: rows hh-1..hh+1, x = -1..64 (xi = x+1 in 0..65)
    for (int idx = t; idx < 3 * 66 * 32; idx += 256) {
        int ky = idx / (66 * 32);
        int r  = idx % (66 * 32);
        int xi = r >> 5;            // 0..65
        int c4 = r & 31;
        int y  = hh + ky - 1;
        int x  = xi - 1;
        float4 v = make_float4(0.f, 0.f, 0.f, 0.f);
        if ((unsigned)y < 64u && (unsigned)x < 64u)
            v = *(const float4*)((const char*)in +
                    ((size_t)(((bb << 6) + y) * 64 + x) << 9) + (c4 << 4));
        *(uint2*)(win + ky * 16896 + xi * 256 + ((c4 << 3) ^ ((xi & 7) << 4))) =
            make_uint2(pk2(v.x, v.y), pk2(v.z, v.w));
    }
    __syncthreads();

    int lane = t & 63, wv = t >> 6;
    int row  = lane & 15, kg = lane >> 4;
    int px0  = wv << 4;

    f32x4 z = {0.f, 0.f, 0.f, 0.f};
    f32x4 acc[2] = {z, z};

    for (int tap = 0; tap < 9; ++tap) {
        int ky = tap / 3, kx = tap - ky * 3;
        int xi = px0 + row + kx;                 // (px + kx - 1) + 1
        const unsigned char* arow = win + ky * 16896 + xi * 256;
        int sw = (xi & 7) << 4;
        const unsigned short* bp = woffT + (size_t)tap * 4096 + (size_t)row * 128 + kg * 8;
        #pragma unroll
        for (int ks = 0; ks < 4; ++ks) {
            bf16x8 a  = *(const bf16x8*)(arow + ((ks * 64 + kg * 16) ^ sw));
            bf16x8 b0 = *(const bf16x8*)(bp + ks * 32);
            bf16x8 b1 = *(const bf16x8*)(bp + 2048 + ks * 32);
            acc[0] = __builtin_amdgcn_mfma_f32_16x16x32_bf16(a, b0, acc[0], 0, 0, 0);
            acc[1] = __builtin_amdgcn_mfma_f32_16x16x32_bf16(a, b1, acc[1], 0, 0, 0);
        }
    }

    #pragma unroll
    for (int n = 0; n < 2; ++n) {
        int oc = n * 16 + row;
        float bv = (oc < NOC) ? bias[oc] : 0.f;
        #pragma unroll
        for (int r = 0; r < 4; ++r) {
            int px = px0 + kg * 4 + r;
            wi32[(size_t)(pix0 + px) * 32 + oc] = acc[n][r] + bv;
        }
    }
}

// ---------------------------------------------------------------- main deform conv (MFMA)
// block = 32 px x 256 F, 4 waves. XCD-swizzled: each XCD gets 128 contiguous
// logical tiles = one full image (input slice ~2.2MB + filtT 0.6MB fits 4MB L2).
__global__ __launch_bounds__(256) void deform_mfma(const float* __restrict__ in,
                                                   const unsigned short* __restrict__ filtT,
                                                   const float* __restrict__ wi32,
                                                   float* __restrict__ out) {
    __shared__ __align__(16) unsigned char Ab[2][32 * 256];   // 16 KB, XOR-swizzled
    __shared__ __align__(16) int   coff[32][9][4];
    __shared__ __align__(16) float fwgt[32][9][4];

    int t    = threadIdx.x;
    int bid  = blockIdx.x;
    int lg   = ((bid & 7) << 7) | (bid >> 3);       // bijective XCD swizzle (1024 = 8*128)
    int bb   = lg >> 7;
    int rem  = lg & 127;
    int hh   = rem >> 1;
    int w0   = (rem & 1) << 5;
    int pix0 = lg << 5;

    // ---- per-(px,tap) sampling params (288 items)
    for (int it = t; it < 288; it += 256) {
        int tap = it >> 5;
        int px  = it & 31;
        const float* wp = wi32 + (size_t)(pix0 + px) * 32;
        float o1 = wp[tap], o2 = wp[9 + tap], mm = wp[18 + tap];
        float mask = 1.f / (1.f + __expf(-mm));
        int ky = tap / 3, kx = tap - ky * 3;
        float py  = (float)(hh - 1 + ky) + o1;
        float pxx = (float)(w0 + px - 1 + kx) + o2;
        float y0f = floorf(py), x0f = floorf(pxx);
        float wy1 = py - y0f,  wy0 = 1.f - wy1;
        float wx1 = pxx - x0f, wx0 = 1.f - wx1;
        float vy0 = (y0f >=  0.f && y0f <= 63.f) ? 1.f : 0.f;
        float vy1 = (y0f >= -1.f && y0f <= 62.f) ? 1.f : 0.f;
        float vx0 = (x0f >=  0.f && x0f <= 63.f) ? 1.f : 0.f;
        float vx1 = (x0f >= -1.f && x0f <= 62.f) ? 1.f : 0.f;
        int y0 = (int)fminf(fmaxf(y0f,       0.f), 63.f);
        int y1 = (int)fminf(fmaxf(y0f + 1.f, 0.f), 63.f);
        int x0 = (int)fminf(fmaxf(x0f,       0.f), 63.f);
        int x1 = (int)fminf(fmaxf(x0f + 1.f, 0.f), 63.f);
        int base = bb << 12;
        coff[px][tap][0] = (base + (y0 << 6) + x0) << 9;
        coff[px][tap][1] = (base + (y0 << 6) + x1) << 9;
        coff[px][tap][2] = (base + (y1 << 6) + x0) << 9;
        coff[px][tap][3] = (base + (y1 << 6) + x1) << 9;
        fwgt[px][tap][0] = wy0 * wx0 * mask * vy0 * vx0;
        fwgt[px][tap][1] = wy0 * wx1 * mask * vy0 * vx1;
        fwgt[px][tap][2] = wy1 * wx0 * mask * vy1 * vx0;
        fwgt[px][tap][3] = wy1 * wx1 * mask * vy1 * vx1;
    }

    int lane = t & 63, wv = t >> 6;
    int row  = lane & 15, kg = lane >> 4;
    int fb   = wv << 6;
    int c4   = t & 31;
    int pxg  = t >> 5;      // 0..7

    const char* ib = (const char*)in;

    auto gather = [&](int tp, int buf) {
        #pragma unroll
        for (int pp = 0; pp < 4; ++pp) {
            int px = pxg + (pp << 3);
            int4   co = *(const int4*)&coff[px][tp][0];
            float4 wg = *(const float4*)&fwgt[px][tp][0];
            int cb = c4 << 4;
            float4 v00 = *(const float4*)(ib + co.x + cb);
            float4 v01 = *(const float4*)(ib + co.y + cb);
            float4 v10 = *(const float4*)(ib + co.z + cb);
            float4 v11 = *(const float4*)(ib + co.w + cb);
            float sx = wg.x * v00.x + wg.y * v01.x + wg.z * v10.x + wg.w * v11.x;
            float sy = wg.x * v00.y + wg.y * v01.y + wg.z * v10.y + wg.w * v11.y;
            float sz = wg.x * v00.z + wg.y * v01.z + wg.z * v10.z + wg.w * v11.z;
            float sw = wg.x * v00.w + wg.y * v01.w + wg.z * v10.w + wg.w * v11.w;
            *(uint2*)(Ab[buf] + ((px << 8) + ((c4 << 3) ^ ((px & 7) << 4)))) =
                make_uint2(pk2(sx, sy), pk2(sz, sw));
        }
    };

    f32x4 z = {0.f, 0.f, 0.f, 0.f};
    f32x4 acc[2][4];
    #pragma unroll
    for (int m = 0; m < 2; ++m)
        #pragma unroll
        for (int n = 0; n < 4; ++n) acc[m][n] = z;

    __syncthreads();          // params ready
    gather(0, 0);
    __syncthreads();          // buf0 ready

    for (int tap = 0; tap < 9; ++tap) {
        int cur = tap & 1;
        // ---- MFMA on current buffer
        const unsigned short* bp = filtT + (size_t)tap * 32768 + (size_t)(fb + row) * 128 + kg * 8;
        #pragma unroll
        for (int ks = 0; ks < 4; ++ks) {
            bf16x8 a[2], bfr[4];
            #pragma unroll
            for (int m = 0; m < 2; ++m)
                a[m] = *(const bf16x8*)(Ab[cur] + (((m * 16 + row) << 8) +
                            ((ks * 64 + kg * 16) ^ ((row & 7) << 4))));
            #pragma unroll
            for (int n = 0; n < 4; ++n)
                bfr[n] = *(const bf16x8*)(bp + n * 2048 + ks * 32);
            #pragma unroll
            for (int m = 0; m < 2; ++m)
                #pragma unroll
                for (int n = 0; n < 4; ++n)
                    acc[m][n] = __builtin_amdgcn_mfma_f32_16x16x32_bf16(a[m], bfr[n], acc[m][n], 0, 0, 0);
        }
        // ---- prefetch-gather next tap into other buffer
        if (tap < 8) gather(tap + 1, cur ^ 1);
        __syncthreads();
    }

    // ---- epilogue
    #pragma unroll
    for (int m = 0; m < 2; ++m)
        #pragma unroll
        for (int r = 0; r < 4; ++r) {
            int px = m * 16 + kg * 4 + r;
            float* op = out + (size_t)(pix0 + px) * 256 + fb + row;
            op[0]  = acc[m][0][r];
            op[16] = acc[m][1][r];
            op[32] = acc[m][2][r];
            op[48] = acc[m][3][r];
        }
}

// ---------------------------------------------------------------- launch
extern "C" void kernel_launch(void* const* d_in, const int* in_sizes, int n_in,
                              void* d_out, int out_size, void* d_ws, size_t ws_size,
                              hipStream_t stream) {
    const float* in   = (const float*)d_in[0];
    const float* kofs = (const float*)d_in[1];
    const float* bias = (const float*)d_in[2];
    const float* filt = (const float*)d_in[3];
    float* out = (float*)d_out;
    float* ws  = (float*)d_ws;

    unsigned short* woffT = (unsigned short*)ws;
    unsigned short* filtT = (unsigned short*)(ws + FILTT_OFF_F);
    float*          wi32  = ws + WI32_OFF_F;

    hipLaunchKernelGGL(repack, dim3(1296), dim3(256), 0, stream, kofs, filt, woffT, filtT);
    hipLaunchKernelGGL(offset_conv_mfma, dim3(512), dim3(256), 0, stream, in, woffT, bias, wi32);
    hipLaunchKernelGGL(deform_mfma, dim3(1024), dim3(256), 0, stream, in, filtT, wi32, out);
}